// Round 16
// baseline (307.774 us; speedup 1.0000x reference)
//
#include <hip/hip_runtime.h>
#include <hip/hip_bf16.h>

#define NN 50000
#define NE 800000

typedef unsigned int u32;
typedef unsigned short u16;
typedef __attribute__((ext_vector_type(2))) _Float16 half2v;
typedef __attribute__((ext_vector_type(8))) _Float16 half8;
typedef __attribute__((ext_vector_type(4))) float f32x4;    // MFMA C/D

__device__ __forceinline__ float silu_f(float x) {
    return x * (1.0f / (1.0f + __expf(-x)));
}
__device__ __forceinline__ u16 f2h_bits(float f) {          // f32 -> f16 (HW RNE)
    union { _Float16 h; u16 u; } c; c.h = (_Float16)f; return c.u;
}
__device__ __forceinline__ _Float16 h_from_bits(u16 u) {
    union { u16 u; _Float16 h; } c; c.u = u; return c.h;
}
__device__ __forceinline__ float h2f(u16 u) {
    return (float)h_from_bits(u);
}

// ---------------------------------------------------------------------------
// Sort-by-DST machinery: histogram -> 2-level exclusive scan -> scatter ranks
// ---------------------------------------------------------------------------
__global__ __launch_bounds__(256) void k_hist(const int* __restrict__ ei, u32* __restrict__ cnt) {
    int e = blockIdx.x * 256 + threadIdx.x;
    atomicAdd(&cnt[ei[NE + e]], 1u);
}

__global__ __launch_bounds__(256) void k_scan_a(const u32* __restrict__ cnt, u32* __restrict__ part) {
    __shared__ u32 sb[256];
    int t = threadIdx.x, i = blockIdx.x * 256 + t;
    u32 v = (i < NN) ? cnt[i] : 0u;
    sb[t] = v; __syncthreads();
    for (int off = 128; off > 0; off >>= 1) { if (t < off) sb[t] += sb[t + off]; __syncthreads(); }
    if (t == 0) part[blockIdx.x] = sb[0];
}

__global__ __launch_bounds__(256) void k_scan_b(u32* __restrict__ part, int nparts) {
    __shared__ u32 sb[256];
    int t = threadIdx.x;
    u32 v = (t < nparts) ? part[t] : 0u;
    sb[t] = v; __syncthreads();
    for (int off = 1; off < 256; off <<= 1) {
        u32 x = (t >= off) ? sb[t - off] : 0u; __syncthreads();
        sb[t] += x; __syncthreads();
    }
    if (t < nparts) part[t] = sb[t] - v;          // exclusive
}

__global__ __launch_bounds__(256) void k_scan_c(const u32* __restrict__ cnt, const u32* __restrict__ part,
                                                u32* __restrict__ row, u32* __restrict__ rowcur) {
    __shared__ u32 sb[256];
    int t = threadIdx.x, i = blockIdx.x * 256 + t;
    u32 v = (i < NN) ? cnt[i] : 0u;
    sb[t] = v; __syncthreads();
    for (int off = 1; off < 256; off <<= 1) {
        u32 x = (t >= off) ? sb[t - off] : 0u; __syncthreads();
        sb[t] += x; __syncthreads();
    }
    if (i < NN) {
        u32 ex = part[blockIdx.x] + sb[t] - v;
        row[i] = ex; rowcur[i] = ex;
    }
    if (i == 0) row[NN] = NE;
}

__global__ __launch_bounds__(256) void k_scatter(const int* __restrict__ ei, u32* __restrict__ rowcur,
                                                 u32* __restrict__ rank, u32* __restrict__ ssd) {
    int e = blockIdx.x * 256 + threadIdx.x;
    u32 s_ = (u32)ei[e];
    u32 d_ = (u32)ei[NE + e];
    u32 pos = atomicAdd(&rowcur[d_], 1u);
    rank[e] = pos;
    ssd[pos] = s_ | (d_ << 16);                   // src | dst<<16 (both < 65536)
}

// ---------------------------------------------------------------------------
// feat f32 -> f16 copy: feat16[n][f] (6.4 MB)
// ---------------------------------------------------------------------------
__global__ __launch_bounds__(256) void k_feat16(const float* __restrict__ feat, u16* __restrict__ feat16) {
    int i = blockIdx.x * 256 + threadIdx.x;      // 400000 threads, 8 elems each
    const float* fp = feat + (size_t)i * 8;
    float4 v0 = *(const float4*)fp;
    float4 v1 = *(const float4*)(fp + 4);
    ushort4 o0{f2h_bits(v0.x), f2h_bits(v0.y), f2h_bits(v0.z), f2h_bits(v0.w)};
    ushort4 o1{f2h_bits(v1.x), f2h_bits(v1.y), f2h_bits(v1.z), f2h_bits(v1.w)};
    u16* op = feat16 + (size_t)i * 8;
    *(ushort4*)op = o0;
    *(ushort4*)(op + 4) = o1;
}

// ---------------------------------------------------------------------------
// Merged weight prep (f16), one kernel:
//   [0, 36864)         : WtT[g][m*64+f] = W_tp[f][m][g]       [64][576]
//   [36864, 38912)     : W1T[h][d]      = W1[d][h]            [64][32]
//   [38912, 39936)     : W2T[n][h]      = (n<9)? W2[h][n] : 0 [16][64]
// ---------------------------------------------------------------------------
__global__ __launch_bounds__(256) void k_weights(const float* __restrict__ Wtp,
                                                 const float* __restrict__ W1,
                                                 const float* __restrict__ W2,
                                                 u16* __restrict__ WtT,
                                                 u16* __restrict__ W1T,
                                                 u16* __restrict__ W2T) {
    int o = blockIdx.x * 256 + threadIdx.x;     // 0..39935
    if (o < 36864) {
        int g = o / 576, k = o % 576;
        int m = k >> 6, f = k & 63;
        WtT[o] = f2h_bits(Wtp[f * 576 + m * 64 + g]);
    } else if (o < 38912) {
        int i = o - 36864;                       // 0..2047
        int n = i >> 5, k = i & 31;
        W1T[i] = f2h_bits(W1[k * 64 + n]);
    } else if (o < 39936) {
        int i = o - 38912;                       // 0..1023
        int n = i >> 6, k = i & 63;
        W2T[i] = (n < 9) ? f2h_bits(W2[k * 9 + n]) : (u16)0;
    }
}

// ---------------------------------------------------------------------------
// K1: per-edge weight MLP via MFMA (r14-proven).
// ---------------------------------------------------------------------------
__global__ __launch_bounds__(256, 2) void k_edge_mlp(
    const float* __restrict__ edge_attr, const float* __restrict__ edge_sh,
    const u16* __restrict__ W1T, const u16* __restrict__ W2T,
    const float* __restrict__ b1, const float* __restrict__ b2,
    const u32* __restrict__ rank,
    u16* __restrict__ s_sorted)            // [NE][12] f16 at rank[e]
{
    __shared__ u16 sW1[64 * 36];           //  4,608 B
    __shared__ u16 sW2[16 * 68];           //  2,176 B
    __shared__ u16 sHid[4][64 * 68];       // 34,816 B (per-wave)
    __shared__ u16 sWout[256 * 12];        //  6,144 B
    const int t  = threadIdx.x;
    const int w  = t >> 6;
    const int l  = t & 63;
    const int e0 = blockIdx.x * 256;
    const int wbase = w << 6;

    // ---- stage W1T (1024 u32) + W2T (512 u32) into LDS ----
    {
        const u32* g1 = (const u32*)W1T;
        u32* l1 = (u32*)sW1;
        #pragma unroll
        for (int i = 0; i < 4; ++i) {
            int idx = i * 256 + t;                 // 0..1023
            int r = idx >> 4, c = idx & 15;
            l1[r * 18 + c] = g1[idx];
        }
        const u32* g2 = (const u32*)W2T;
        u32* l2 = (u32*)sW2;
        #pragma unroll
        for (int i = 0; i < 2; ++i) {
            int idx = i * 256 + t;                 // 0..511
            int r = idx >> 5, c = idx & 31;
            l2[r * 34 + c] = g2[idx];
        }
    }

    // ---- A-frags: attr rows -> f16 (8 contig k per lane) ----
    half8 aA[4];
    #pragma unroll
    for (int et = 0; et < 4; ++et) {
        const int e = e0 + wbase + (et << 4) + (l & 15);
        const float* ap = edge_attr + (size_t)e * 32 + ((l >> 4) << 3);
        float4 v0 = *(const float4*)ap;
        float4 v1 = *(const float4*)(ap + 4);
        aA[et] = half8{(_Float16)v0.x, (_Float16)v0.y, (_Float16)v0.z, (_Float16)v0.w,
                       (_Float16)v1.x, (_Float16)v1.y, (_Float16)v1.z, (_Float16)v1.w};
    }
    __syncthreads();

    // ---- GEMM1: [256x32] @ [32x64], K=32 ----
    f32x4 acc1[4][4] = {};
    {
        half8 bB[4];
        #pragma unroll
        for (int nt = 0; nt < 4; ++nt)
            bB[nt] = *(const half8*)&sW1[((nt << 4) + (l & 15)) * 36 + ((l >> 4) << 3)];
        #pragma unroll
        for (int et = 0; et < 4; ++et)
            #pragma unroll
            for (int nt = 0; nt < 4; ++nt)
                acc1[et][nt] = __builtin_amdgcn_mfma_f32_16x16x32_f16(aA[et], bB[nt], acc1[et][nt], 0, 0, 0);
    }

    // ---- +b1, silu -> per-wave LDS hid tile [64][68] f16 ----
    {
        float b1v[4];
        #pragma unroll
        for (int nt = 0; nt < 4; ++nt) b1v[nt] = b1[(nt << 4) + (l & 15)];
        #pragma unroll
        for (int et = 0; et < 4; ++et)
            #pragma unroll
            for (int nt = 0; nt < 4; ++nt)
                #pragma unroll
                for (int rg = 0; rg < 4; ++rg) {
                    int r = (et << 4) + ((l >> 4) << 2) + rg;
                    int c = (nt << 4) + (l & 15);
                    sHid[w][r * 68 + c] = f2h_bits(silu_f(acc1[et][nt][rg] + b1v[nt]));
                }
    }
    __syncthreads();

    // ---- GEMM2: [256x64] @ [64x16], K=64 ----
    f32x4 acc2[4] = {};
    #pragma unroll
    for (int tt = 0; tt < 2; ++tt) {
        half8 b2f = *(const half8*)&sW2[(l & 15) * 68 + tt * 32 + ((l >> 4) << 3)];
        #pragma unroll
        for (int et = 0; et < 4; ++et) {
            half8 a2 = *(const half8*)&sHid[w][((et << 4) + (l & 15)) * 68 + tt * 32 + ((l >> 4) << 3)];
            acc2[et] = __builtin_amdgcn_mfma_f32_16x16x32_f16(a2, b2f, acc2[et], 0, 0, 0);
        }
    }

    // ---- +b2 -> LDS w tile [256][12] ----
    {
        const int m = l & 15;
        if (m < 9) {
            const float b2v = b2[m];
            #pragma unroll
            for (int et = 0; et < 4; ++et)
                #pragma unroll
                for (int rg = 0; rg < 4; ++rg) {
                    int r = wbase + (et << 4) + ((l >> 4) << 2) + rg;
                    sWout[r * 12 + m] = f2h_bits(acc2[et][rg] + b2v);
                }
        }
    }
    __syncthreads();

    // ---- proven tail ----
    const size_t e = (size_t)e0 + t;
    const float* sh = edge_sh + e * 9;
    u16 sw[12];
    #pragma unroll
    for (int m = 0; m < 9; ++m) sw[m] = f2h_bits(sh[m] * h2f(sWout[t * 12 + m]));
    sw[9] = sw[10] = sw[11] = 0;

    u16* dp = s_sorted + (size_t)rank[e] * 12;
    ushort4 v0{sw[0], sw[1], sw[2],  sw[3]};
    ushort4 v1{sw[4], sw[5], sw[6],  sw[7]};
    ushort4 v2{sw[8], sw[9], sw[10], sw[11]};
    *(ushort4*)(dp + 0) = v0;
    *(ushort4*)(dp + 4) = v1;
    *(ushort4*)(dp + 8) = v2;
}

// ---------------------------------------------------------------------------
// K3: MFMA combine, f16 datapath, LDS-staged B operand.  EXACT r14 structure
// (89 µs proven; r15's half-stage regressed -14% — occupancy did not rise).
// ssd packs src|dst<<16: dst needed only at p0 and p0+255.
// ---------------------------------------------------------------------------
union SmU {
    u16 wt[64 * 584];      // 74,752 B  (staged WtT, padded rows)
    u16 msg[256 * 68];     // 34,816 B  (C spill, f16)
};

__global__ __launch_bounds__(256, 2) void k_combine_mfma(
    const u32* __restrict__ ssd,  const u32* __restrict__ row,
    const u16* __restrict__ s_sorted,
    const u16* __restrict__ feat16, const u16* __restrict__ WtT,
    float* __restrict__ out)
{
    __shared__ SmU sm;
    const int t  = threadIdx.x;
    const int w  = t >> 6;
    const int l  = t & 63;
    const int p0 = blockIdx.x * 256;
    const int rbase = w << 6;

    // ---- hoisted global loads: srcs, 8 feat gathers, s ----
    u32 srcr[4];
    #pragma unroll
    for (int et = 0; et < 4; ++et)
        srcr[et] = ssd[p0 + rbase + (et << 4) + (l & 15)] & 0xFFFFu;

    half8 h16[4][2];                        // [et][fhalf]
    #pragma unroll
    for (int et = 0; et < 4; ++et)
        #pragma unroll
        for (int fh = 0; fh < 2; ++fh)
            h16[et][fh] = *(const half8*)(feat16 +
                (size_t)srcr[et] * 64 + (fh << 5) + ((l >> 4) << 3));

    half2v s2[4][9];                        // {s,s} pairs
    #pragma unroll
    for (int et = 0; et < 4; ++et) {
        const u16* sp = s_sorted + (size_t)(p0 + rbase + (et << 4) + (l & 15)) * 12;
        #pragma unroll
        for (int m = 0; m < 9; ++m) {
            _Float16 sv = h_from_bits(sp[m]);
            s2[et][m] = half2v{sv, sv};
        }
    }

    // ---- stage WtT [64][576] -> LDS [64][584] in 16B chunks ----
    {
        const uint4* gsrc = (const uint4*)WtT;         // [64*72] 16B chunks
        uint4* lw = (uint4*)sm.wt;                     // 584/8 = 73 chunks/row
        #pragma unroll
        for (int i = 0; i < 18; ++i) {
            int c = i * 256 + t;                       // 0..4607
            int r = c / 72, q = c - r * 72;
            lw[r * 73 + q] = gsrc[c];
        }
    }
    __syncthreads();

    f32x4 acc[4][4] = {};
    #pragma unroll
    for (int fhalf = 0; fhalf < 2; ++fhalf) {
        #pragma unroll
        for (int m = 0; m < 9; ++m) {
            const int tt = (m << 1) + fhalf;          // K-slice: k = tt*32 ..
            half8 bfr[4];
            #pragma unroll
            for (int gt = 0; gt < 4; ++gt)
                bfr[gt] = *(const half8*)&sm.wt[
                    (((gt << 4) + (l & 15)) * 584) + tt * 32 + ((l >> 4) << 3)];
            #pragma unroll
            for (int et = 0; et < 4; ++et) {
                union { half2v h2[4]; half8 v; } A;
                const union { half8 v; half2v h2[4]; } H = { h16[et][fhalf] };
                A.h2[0] = H.h2[0] * s2[et][m];         // v_pk_mul_f16
                A.h2[1] = H.h2[1] * s2[et][m];
                A.h2[2] = H.h2[2] * s2[et][m];
                A.h2[3] = H.h2[3] * s2[et][m];
                #pragma unroll
                for (int gt = 0; gt < 4; ++gt)
                    acc[et][gt] = __builtin_amdgcn_mfma_f32_16x16x32_f16(A.v, bfr[gt], acc[et][gt], 0, 0, 0);
            }
        }
    }
    __syncthreads();   // all B-reads done before msg overwrites the union

    // ---- C tiles -> LDS msg[256][68] f16 (disjoint cells) ----
    #pragma unroll
    for (int et = 0; et < 4; ++et)
        #pragma unroll
        for (int gt = 0; gt < 4; ++gt)
            #pragma unroll
            for (int rg = 0; rg < 4; ++rg) {
                int rloc = rbase + (et << 4) + ((l >> 4) << 2) + rg;   // C row = edge
                int col  = (gt << 4) + (l & 15);                       // C col = g
                sm.msg[rloc * 68 + col] = f2h_bits(acc[et][gt][rg]);
            }
    __syncthreads();

    // ---- segmented per-node reduction; one atomic per (node,g) per block ----
    const int dfirst = (int)(ssd[p0] >> 16);
    const int dlast  = (int)(ssd[p0 + 255] >> 16);
    for (int n = dfirst + w; n <= dlast; n += 4) {
        int a = (int)row[n]     - p0; if (a < 0)   a = 0;
        int b = (int)row[n + 1] - p0; if (b > 256) b = 256;
        if (a < b) {
            float v = 0.f;
            for (int p = a; p < b; ++p) v += h2f(sm.msg[p * 68 + l]);
            atomicAdd(out + (size_t)n * 64 + l, v * 0.25f);    // 1/sqrt(16)
        }
    }
}

// ---------------------------------------------------------------------------
// K4: FiLM, in-place on d_out.
// ---------------------------------------------------------------------------
__global__ __launch_bounds__(256) void k_film(
    const float* __restrict__ c_noise,
    const float* __restrict__ Wn1, const float* __restrict__ bn1,
    const float* __restrict__ Wn2, const float* __restrict__ bn2,
    float* __restrict__ out)
{
    const int n    = (blockIdx.x * 256 + threadIdx.x) >> 6;
    const int lane = threadIdx.x & 63;
    const float c  = c_noise[n];
    const float hid = silu_f(fmaf(c, Wn1[lane], bn1[lane]));
    float g = bn2[lane], b = bn2[64 + lane];
    for (int h = 0; h < 64; ++h) {
        const float hv = __shfl(hid, h, 64);
        g = fmaf(hv, Wn2[h * 128 + lane],      g);
        b = fmaf(hv, Wn2[h * 128 + 64 + lane], b);
    }
    const size_t i = (size_t)n * 64 + lane;
    out[i] = fmaf(out[i], 1.f + g, b);
}

// ---------------------------------------------------------------------------
extern "C" void kernel_launch(void* const* d_in, const int* in_sizes, int n_in,
                              void* d_out, int out_size, void* d_ws, size_t ws_size,
                              hipStream_t stream) {
    const float* features   = (const float*)d_in[0];
    const int*   edge_index = (const int*)  d_in[1];
    const float* edge_attr  = (const float*)d_in[2];
    const float* edge_sh    = (const float*)d_in[3];
    const float* c_noise    = (const float*)d_in[4];
    const float* W1  = (const float*)d_in[5];
    const float* b1  = (const float*)d_in[6];
    const float* W2  = (const float*)d_in[7];
    const float* b2  = (const float*)d_in[8];
    const float* Wtp = (const float*)d_in[9];
    const float* Wn1 = (const float*)d_in[10];
    const float* bn1 = (const float*)d_in[11];
    const float* Wn2 = (const float*)d_in[12];
    const float* bn2 = (const float*)d_in[13];
    float* out = (float*)d_out;

    char* ws = (char*)d_ws;
    u16* feat16   = (u16*)(ws);                    //  6,400,000 B
    u16* s_sorted = (u16*)(ws +  6400000);         // 19,200,000 B
    u32* ssd      = (u32*)(ws + 25600000);         //  3,200,000 B
    u32* rank     = (u32*)(ws + 28800000);         //  3,200,000 B
    u32* row      = (u32*)(ws + 32000000);         //    200,016 B (NN+1)
    u32* rowcur   = (u32*)(ws + 32200016);         //    200,000 B
    u32* cnt      = (u32*)(ws + 32400016);         //    200,000 B
    u32* part     = (u32*)(ws + 32600016);         //      1,024 B
    u16* WtT      = (u16*)(ws + 32601040);         //     73,728 B
    u16* W1T      = (u16*)(ws + 32674768);         //      4,096 B
    u16* W2T      = (u16*)(ws + 32678864);         //      2,048 B  (end ~32.7 MB)

    const int nparts = (NN + 255) / 256;           // 196

    hipMemsetAsync(cnt, 0, (size_t)NN * 4, stream);
    hipMemsetAsync(out, 0, (size_t)NN * 64 * sizeof(float), stream);

    k_hist   <<<NE / 256, 256, 0, stream>>>(edge_index, cnt);
    k_scan_a <<<nparts, 256, 0, stream>>>(cnt, part);
    k_scan_b <<<1, 256, 0, stream>>>(part, nparts);
    k_scan_c <<<nparts, 256, 0, stream>>>(cnt, part, row, rowcur);
    k_scatter<<<NE / 256, 256, 0, stream>>>(edge_index, rowcur, rank, ssd);

    k_feat16 <<<(NN * 64 / 8 + 255) / 256, 256, 0, stream>>>(features, feat16);
    k_weights<<<(39936 + 255) / 256, 256, 0, stream>>>(Wtp, W1, W2, WtT, W1T, W2T);

    k_edge_mlp<<<NE / 256, 256, 0, stream>>>(edge_attr, edge_sh, W1T, W2T, b1, b2,
                                             rank, s_sorted);

    k_combine_mfma<<<NE / 256, 256, 0, stream>>>(ssd, row, s_sorted,
                                                 feat16, WtT, out);

    k_film<<<(NN * 64) / 256, 256, 0, stream>>>(c_noise, Wn1, bn1, Wn2, bn2, out);
}

// Round 17
// 300.698 us; speedup vs baseline: 1.0235x; 1.0235x over previous
//
#include <hip/hip_runtime.h>
#include <hip/hip_bf16.h>

#define NN 50000
#define NE 800000

typedef unsigned int u32;
typedef unsigned short u16;
typedef __attribute__((ext_vector_type(2))) _Float16 half2v;
typedef __attribute__((ext_vector_type(8))) _Float16 half8;
typedef __attribute__((ext_vector_type(4))) float f32x4;    // MFMA C/D

__device__ __forceinline__ float silu_f(float x) {
    return x * (1.0f / (1.0f + __expf(-x)));
}
__device__ __forceinline__ u16 f2h_bits(float f) {          // f32 -> f16 (HW RNE)
    union { _Float16 h; u16 u; } c; c.h = (_Float16)f; return c.u;
}
__device__ __forceinline__ _Float16 h_from_bits(u16 u) {
    union { u16 u; _Float16 h; } c; c.u = u; return c.h;
}
__device__ __forceinline__ float h2f(u16 u) {
    return (float)h_from_bits(u);
}

// ---------------------------------------------------------------------------
// Sort-by-DST machinery: histogram -> 2-level exclusive scan -> scatter ranks
// ---------------------------------------------------------------------------
__global__ __launch_bounds__(256) void k_hist(const int* __restrict__ ei, u32* __restrict__ cnt) {
    int e = blockIdx.x * 256 + threadIdx.x;
    atomicAdd(&cnt[ei[NE + e]], 1u);
}

__global__ __launch_bounds__(256) void k_scan_a(const u32* __restrict__ cnt, u32* __restrict__ part) {
    __shared__ u32 sb[256];
    int t = threadIdx.x, i = blockIdx.x * 256 + t;
    u32 v = (i < NN) ? cnt[i] : 0u;
    sb[t] = v; __syncthreads();
    for (int off = 128; off > 0; off >>= 1) { if (t < off) sb[t] += sb[t + off]; __syncthreads(); }
    if (t == 0) part[blockIdx.x] = sb[0];
}

__global__ __launch_bounds__(256) void k_scan_b(u32* __restrict__ part, int nparts) {
    __shared__ u32 sb[256];
    int t = threadIdx.x;
    u32 v = (t < nparts) ? part[t] : 0u;
    sb[t] = v; __syncthreads();
    for (int off = 1; off < 256; off <<= 1) {
        u32 x = (t >= off) ? sb[t - off] : 0u; __syncthreads();
        sb[t] += x; __syncthreads();
    }
    if (t < nparts) part[t] = sb[t] - v;          // exclusive
}

__global__ __launch_bounds__(256) void k_scan_c(const u32* __restrict__ cnt, const u32* __restrict__ part,
                                                u32* __restrict__ row, u32* __restrict__ rowcur) {
    __shared__ u32 sb[256];
    int t = threadIdx.x, i = blockIdx.x * 256 + t;
    u32 v = (i < NN) ? cnt[i] : 0u;
    sb[t] = v; __syncthreads();
    for (int off = 1; off < 256; off <<= 1) {
        u32 x = (t >= off) ? sb[t - off] : 0u; __syncthreads();
        sb[t] += x; __syncthreads();
    }
    if (i < NN) {
        u32 ex = part[blockIdx.x] + sb[t] - v;
        row[i] = ex; rowcur[i] = ex;
    }
    if (i == 0) row[NN] = NE;
}

__global__ __launch_bounds__(256) void k_scatter(const int* __restrict__ ei, u32* __restrict__ rowcur,
                                                 u32* __restrict__ rank, u32* __restrict__ ssd) {
    int e = blockIdx.x * 256 + threadIdx.x;
    u32 s_ = (u32)ei[e];
    u32 d_ = (u32)ei[NE + e];
    u32 pos = atomicAdd(&rowcur[d_], 1u);
    rank[e] = pos;
    ssd[pos] = s_ | (d_ << 16);                   // src | dst<<16 (both < 65536)
}

// ---------------------------------------------------------------------------
// feat f32 -> f16 copy: feat16[n][f] (6.4 MB)
// ---------------------------------------------------------------------------
__global__ __launch_bounds__(256) void k_feat16(const float* __restrict__ feat, u16* __restrict__ feat16) {
    int i = blockIdx.x * 256 + threadIdx.x;      // 400000 threads, 8 elems each
    const float* fp = feat + (size_t)i * 8;
    float4 v0 = *(const float4*)fp;
    float4 v1 = *(const float4*)(fp + 4);
    ushort4 o0{f2h_bits(v0.x), f2h_bits(v0.y), f2h_bits(v0.z), f2h_bits(v0.w)};
    ushort4 o1{f2h_bits(v1.x), f2h_bits(v1.y), f2h_bits(v1.z), f2h_bits(v1.w)};
    u16* op = feat16 + (size_t)i * 8;
    *(ushort4*)op = o0;
    *(ushort4*)(op + 4) = o1;
}

// ---------------------------------------------------------------------------
// Merged weight prep (f16), one kernel:
//   [0, 36864)         : WtT[g][m*64+f] = W_tp[f][m][g]       [64][576]
//   [36864, 38912)     : W1T[h][d]      = W1[d][h]            [64][32]
//   [38912, 39936)     : W2T[n][h]      = (n<9)? W2[h][n] : 0 [16][64]
// ---------------------------------------------------------------------------
__global__ __launch_bounds__(256) void k_weights(const float* __restrict__ Wtp,
                                                 const float* __restrict__ W1,
                                                 const float* __restrict__ W2,
                                                 u16* __restrict__ WtT,
                                                 u16* __restrict__ W1T,
                                                 u16* __restrict__ W2T) {
    int o = blockIdx.x * 256 + threadIdx.x;     // 0..39935
    if (o < 36864) {
        int g = o / 576, k = o % 576;
        int m = k >> 6, f = k & 63;
        WtT[o] = f2h_bits(Wtp[f * 576 + m * 64 + g]);
    } else if (o < 38912) {
        int i = o - 36864;                       // 0..2047
        int n = i >> 5, k = i & 31;
        W1T[i] = f2h_bits(W1[k * 64 + n]);
    } else if (o < 39936) {
        int i = o - 38912;                       // 0..1023
        int n = i >> 6, k = i & 63;
        W2T[i] = (n < 9) ? f2h_bits(W2[k * 9 + n]) : (u16)0;
    }
}

// ---------------------------------------------------------------------------
// K1: per-edge weight MLP via MFMA (r14-proven).
// ---------------------------------------------------------------------------
__global__ __launch_bounds__(256, 2) void k_edge_mlp(
    const float* __restrict__ edge_attr, const float* __restrict__ edge_sh,
    const u16* __restrict__ W1T, const u16* __restrict__ W2T,
    const float* __restrict__ b1, const float* __restrict__ b2,
    const u32* __restrict__ rank,
    u16* __restrict__ s_sorted)            // [NE][12] f16 at rank[e]
{
    __shared__ u16 sW1[64 * 36];           //  4,608 B
    __shared__ u16 sW2[16 * 68];           //  2,176 B
    __shared__ u16 sHid[4][64 * 68];       // 34,816 B (per-wave)
    __shared__ u16 sWout[256 * 12];        //  6,144 B
    const int t  = threadIdx.x;
    const int w  = t >> 6;
    const int l  = t & 63;
    const int e0 = blockIdx.x * 256;
    const int wbase = w << 6;

    // ---- stage W1T (1024 u32) + W2T (512 u32) into LDS ----
    {
        const u32* g1 = (const u32*)W1T;
        u32* l1 = (u32*)sW1;
        #pragma unroll
        for (int i = 0; i < 4; ++i) {
            int idx = i * 256 + t;                 // 0..1023
            int r = idx >> 4, c = idx & 15;
            l1[r * 18 + c] = g1[idx];
        }
        const u32* g2 = (const u32*)W2T;
        u32* l2 = (u32*)sW2;
        #pragma unroll
        for (int i = 0; i < 2; ++i) {
            int idx = i * 256 + t;                 // 0..511
            int r = idx >> 5, c = idx & 31;
            l2[r * 34 + c] = g2[idx];
        }
    }

    // ---- A-frags: attr rows -> f16 (8 contig k per lane) ----
    half8 aA[4];
    #pragma unroll
    for (int et = 0; et < 4; ++et) {
        const int e = e0 + wbase + (et << 4) + (l & 15);
        const float* ap = edge_attr + (size_t)e * 32 + ((l >> 4) << 3);
        float4 v0 = *(const float4*)ap;
        float4 v1 = *(const float4*)(ap + 4);
        aA[et] = half8{(_Float16)v0.x, (_Float16)v0.y, (_Float16)v0.z, (_Float16)v0.w,
                       (_Float16)v1.x, (_Float16)v1.y, (_Float16)v1.z, (_Float16)v1.w};
    }
    __syncthreads();

    // ---- GEMM1: [256x32] @ [32x64], K=32 ----
    f32x4 acc1[4][4] = {};
    {
        half8 bB[4];
        #pragma unroll
        for (int nt = 0; nt < 4; ++nt)
            bB[nt] = *(const half8*)&sW1[((nt << 4) + (l & 15)) * 36 + ((l >> 4) << 3)];
        #pragma unroll
        for (int et = 0; et < 4; ++et)
            #pragma unroll
            for (int nt = 0; nt < 4; ++nt)
                acc1[et][nt] = __builtin_amdgcn_mfma_f32_16x16x32_f16(aA[et], bB[nt], acc1[et][nt], 0, 0, 0);
    }

    // ---- +b1, silu -> per-wave LDS hid tile [64][68] f16 ----
    {
        float b1v[4];
        #pragma unroll
        for (int nt = 0; nt < 4; ++nt) b1v[nt] = b1[(nt << 4) + (l & 15)];
        #pragma unroll
        for (int et = 0; et < 4; ++et)
            #pragma unroll
            for (int nt = 0; nt < 4; ++nt)
                #pragma unroll
                for (int rg = 0; rg < 4; ++rg) {
                    int r = (et << 4) + ((l >> 4) << 2) + rg;
                    int c = (nt << 4) + (l & 15);
                    sHid[w][r * 68 + c] = f2h_bits(silu_f(acc1[et][nt][rg] + b1v[nt]));
                }
    }
    __syncthreads();

    // ---- GEMM2: [256x64] @ [64x16], K=64 ----
    f32x4 acc2[4] = {};
    #pragma unroll
    for (int tt = 0; tt < 2; ++tt) {
        half8 b2f = *(const half8*)&sW2[(l & 15) * 68 + tt * 32 + ((l >> 4) << 3)];
        #pragma unroll
        for (int et = 0; et < 4; ++et) {
            half8 a2 = *(const half8*)&sHid[w][((et << 4) + (l & 15)) * 68 + tt * 32 + ((l >> 4) << 3)];
            acc2[et] = __builtin_amdgcn_mfma_f32_16x16x32_f16(a2, b2f, acc2[et], 0, 0, 0);
        }
    }

    // ---- +b2 -> LDS w tile [256][12] ----
    {
        const int m = l & 15;
        if (m < 9) {
            const float b2v = b2[m];
            #pragma unroll
            for (int et = 0; et < 4; ++et)
                #pragma unroll
                for (int rg = 0; rg < 4; ++rg) {
                    int r = wbase + (et << 4) + ((l >> 4) << 2) + rg;
                    sWout[r * 12 + m] = f2h_bits(acc2[et][rg] + b2v);
                }
        }
    }
    __syncthreads();

    // ---- proven tail ----
    const size_t e = (size_t)e0 + t;
    const float* sh = edge_sh + e * 9;
    u16 sw[12];
    #pragma unroll
    for (int m = 0; m < 9; ++m) sw[m] = f2h_bits(sh[m] * h2f(sWout[t * 12 + m]));
    sw[9] = sw[10] = sw[11] = 0;

    u16* dp = s_sorted + (size_t)rank[e] * 12;
    ushort4 v0{sw[0], sw[1], sw[2],  sw[3]};
    ushort4 v1{sw[4], sw[5], sw[6],  sw[7]};
    ushort4 v2{sw[8], sw[9], sw[10], sw[11]};
    *(ushort4*)(dp + 0) = v0;
    *(ushort4*)(dp + 4) = v1;
    *(ushort4*)(dp + 8) = v2;
}

// ---------------------------------------------------------------------------
// K3: MFMA combine — 512 threads (8 waves x 2 e-tiles).  Same 256-edge block,
// same single WtT stage + LDS layout as r14/r16 (89 µs proven).  Halved
// per-wave accumulator (32 AGPR) drops total regs ~164 -> ~102 <= 128, which
// per the m69 occupancy model doubles waves/SIMD (2 -> 4).  No extra barriers.
// ---------------------------------------------------------------------------
union SmU {
    u16 wt[64 * 584];      // 74,752 B  (staged WtT, padded rows)
    u16 msg[256 * 68];     // 34,816 B  (C spill, f16)
};

__global__ __launch_bounds__(512, 4) void k_combine_mfma(
    const u32* __restrict__ ssd,  const u32* __restrict__ row,
    const u16* __restrict__ s_sorted,
    const u16* __restrict__ feat16, const u16* __restrict__ WtT,
    float* __restrict__ out)
{
    __shared__ SmU sm;
    const int t  = threadIdx.x;
    const int w  = t >> 6;                 // 0..7
    const int l  = t & 63;
    const int p0 = blockIdx.x * 256;
    const int rbase = w << 5;              // 32 edges per wave

    // ---- hoisted global loads: srcs, 4 feat gathers, s ----
    u32 srcr[2];
    #pragma unroll
    for (int et = 0; et < 2; ++et)
        srcr[et] = ssd[p0 + rbase + (et << 4) + (l & 15)] & 0xFFFFu;

    half8 h16[2][2];                        // [et][fhalf]
    #pragma unroll
    for (int et = 0; et < 2; ++et)
        #pragma unroll
        for (int fh = 0; fh < 2; ++fh)
            h16[et][fh] = *(const half8*)(feat16 +
                (size_t)srcr[et] * 64 + (fh << 5) + ((l >> 4) << 3));

    half2v s2[2][9];                        // {s,s} pairs
    #pragma unroll
    for (int et = 0; et < 2; ++et) {
        const u16* sp = s_sorted + (size_t)(p0 + rbase + (et << 4) + (l & 15)) * 12;
        #pragma unroll
        for (int m = 0; m < 9; ++m) {
            _Float16 sv = h_from_bits(sp[m]);
            s2[et][m] = half2v{sv, sv};
        }
    }

    // ---- stage WtT [64][576] -> LDS [64][584] in 16B chunks ----
    {
        const uint4* gsrc = (const uint4*)WtT;         // [64*72] 16B chunks
        uint4* lw = (uint4*)sm.wt;                     // 584/8 = 73 chunks/row
        #pragma unroll
        for (int i = 0; i < 9; ++i) {
            int c = i * 512 + t;                       // 0..4607
            int r = c / 72, q = c - r * 72;
            lw[r * 73 + q] = gsrc[c];
        }
    }
    __syncthreads();

    f32x4 acc[2][4] = {};
    #pragma unroll
    for (int fhalf = 0; fhalf < 2; ++fhalf) {
        #pragma unroll
        for (int m = 0; m < 9; ++m) {
            const int tt = (m << 1) + fhalf;          // K-slice: k = tt*32 ..
            half8 bfr[4];
            #pragma unroll
            for (int gt = 0; gt < 4; ++gt)
                bfr[gt] = *(const half8*)&sm.wt[
                    (((gt << 4) + (l & 15)) * 584) + tt * 32 + ((l >> 4) << 3)];
            #pragma unroll
            for (int et = 0; et < 2; ++et) {
                union { half2v h2[4]; half8 v; } A;
                const union { half8 v; half2v h2[4]; } H = { h16[et][fhalf] };
                A.h2[0] = H.h2[0] * s2[et][m];         // v_pk_mul_f16
                A.h2[1] = H.h2[1] * s2[et][m];
                A.h2[2] = H.h2[2] * s2[et][m];
                A.h2[3] = H.h2[3] * s2[et][m];
                #pragma unroll
                for (int gt = 0; gt < 4; ++gt)
                    acc[et][gt] = __builtin_amdgcn_mfma_f32_16x16x32_f16(A.v, bfr[gt], acc[et][gt], 0, 0, 0);
            }
        }
    }
    __syncthreads();   // all B-reads done before msg overwrites the union

    // ---- C tiles -> LDS msg[256][68] f16 (disjoint cells) ----
    #pragma unroll
    for (int et = 0; et < 2; ++et)
        #pragma unroll
        for (int gt = 0; gt < 4; ++gt)
            #pragma unroll
            for (int rg = 0; rg < 4; ++rg) {
                int rloc = rbase + (et << 4) + ((l >> 4) << 2) + rg;   // C row = edge
                int col  = (gt << 4) + (l & 15);                       // C col = g
                sm.msg[rloc * 68 + col] = f2h_bits(acc[et][gt][rg]);
            }
    __syncthreads();

    // ---- segmented per-node reduction; one atomic per (node,g) per block ----
    const int dfirst = (int)(ssd[p0] >> 16);
    const int dlast  = (int)(ssd[p0 + 255] >> 16);
    for (int n = dfirst + w; n <= dlast; n += 8) {
        int a = (int)row[n]     - p0; if (a < 0)   a = 0;
        int b = (int)row[n + 1] - p0; if (b > 256) b = 256;
        if (a < b) {
            float v = 0.f;
            for (int p = a; p < b; ++p) v += h2f(sm.msg[p * 68 + l]);
            atomicAdd(out + (size_t)n * 64 + l, v * 0.25f);    // 1/sqrt(16)
        }
    }
}

// ---------------------------------------------------------------------------
// K4: FiLM, in-place on d_out.
// ---------------------------------------------------------------------------
__global__ __launch_bounds__(256) void k_film(
    const float* __restrict__ c_noise,
    const float* __restrict__ Wn1, const float* __restrict__ bn1,
    const float* __restrict__ Wn2, const float* __restrict__ bn2,
    float* __restrict__ out)
{
    const int n    = (blockIdx.x * 256 + threadIdx.x) >> 6;
    const int lane = threadIdx.x & 63;
    const float c  = c_noise[n];
    const float hid = silu_f(fmaf(c, Wn1[lane], bn1[lane]));
    float g = bn2[lane], b = bn2[64 + lane];
    for (int h = 0; h < 64; ++h) {
        const float hv = __shfl(hid, h, 64);
        g = fmaf(hv, Wn2[h * 128 + lane],      g);
        b = fmaf(hv, Wn2[h * 128 + 64 + lane], b);
    }
    const size_t i = (size_t)n * 64 + lane;
    out[i] = fmaf(out[i], 1.f + g, b);
}

// ---------------------------------------------------------------------------
extern "C" void kernel_launch(void* const* d_in, const int* in_sizes, int n_in,
                              void* d_out, int out_size, void* d_ws, size_t ws_size,
                              hipStream_t stream) {
    const float* features   = (const float*)d_in[0];
    const int*   edge_index = (const int*)  d_in[1];
    const float* edge_attr  = (const float*)d_in[2];
    const float* edge_sh    = (const float*)d_in[3];
    const float* c_noise    = (const float*)d_in[4];
    const float* W1  = (const float*)d_in[5];
    const float* b1  = (const float*)d_in[6];
    const float* W2  = (const float*)d_in[7];
    const float* b2  = (const float*)d_in[8];
    const float* Wtp = (const float*)d_in[9];
    const float* Wn1 = (const float*)d_in[10];
    const float* bn1 = (const float*)d_in[11];
    const float* Wn2 = (const float*)d_in[12];
    const float* bn2 = (const float*)d_in[13];
    float* out = (float*)d_out;

    char* ws = (char*)d_ws;
    u16* feat16   = (u16*)(ws);                    //  6,400,000 B
    u16* s_sorted = (u16*)(ws +  6400000);         // 19,200,000 B
    u32* ssd      = (u32*)(ws + 25600000);         //  3,200,000 B
    u32* rank     = (u32*)(ws + 28800000);         //  3,200,000 B
    u32* row      = (u32*)(ws + 32000000);         //    200,016 B (NN+1)
    u32* rowcur   = (u32*)(ws + 32200016);         //    200,000 B
    u32* cnt      = (u32*)(ws + 32400016);         //    200,000 B
    u32* part     = (u32*)(ws + 32600016);         //      1,024 B
    u16* WtT      = (u16*)(ws + 32601040);         //     73,728 B
    u16* W1T      = (u16*)(ws + 32674768);         //      4,096 B
    u16* W2T      = (u16*)(ws + 32678864);         //      2,048 B  (end ~32.7 MB)

    const int nparts = (NN + 255) / 256;           // 196

    hipMemsetAsync(cnt, 0, (size_t)NN * 4, stream);
    hipMemsetAsync(out, 0, (size_t)NN * 64 * sizeof(float), stream);

    k_hist   <<<NE / 256, 256, 0, stream>>>(edge_index, cnt);
    k_scan_a <<<nparts, 256, 0, stream>>>(cnt, part);
    k_scan_b <<<1, 256, 0, stream>>>(part, nparts);
    k_scan_c <<<nparts, 256, 0, stream>>>(cnt, part, row, rowcur);
    k_scatter<<<NE / 256, 256, 0, stream>>>(edge_index, rowcur, rank, ssd);

    k_feat16 <<<(NN * 64 / 8 + 255) / 256, 256, 0, stream>>>(features, feat16);
    k_weights<<<(39936 + 255) / 256, 256, 0, stream>>>(Wtp, W1, W2, WtT, W1T, W2T);

    k_edge_mlp<<<NE / 256, 256, 0, stream>>>(edge_attr, edge_sh, W1T, W2T, b1, b2,
                                             rank, s_sorted);

    k_combine_mfma<<<NE / 256, 512, 0, stream>>>(ssd, row, s_sorted,
                                                 feat16, WtT, out);

    k_film<<<(NN * 64) / 256, 256, 0, stream>>>(c_noise, Wn1, bn1, Wn2, bn2, out);
}

// Round 18
// 258.924 us; speedup vs baseline: 1.1887x; 1.1613x over previous
//
#include <hip/hip_runtime.h>
#include <hip/hip_bf16.h>

#define NN 50000
#define NE 800000

typedef unsigned int u32;
typedef unsigned short u16;
typedef __attribute__((ext_vector_type(2))) _Float16 half2v;
typedef __attribute__((ext_vector_type(8))) _Float16 half8;
typedef __attribute__((ext_vector_type(4))) float f32x4;    // MFMA C/D

__device__ __forceinline__ float silu_f(float x) {
    return x * (1.0f / (1.0f + __expf(-x)));
}
__device__ __forceinline__ u16 f2h_bits(float f) {          // f32 -> f16 (HW RNE)
    union { _Float16 h; u16 u; } c; c.h = (_Float16)f; return c.u;
}
__device__ __forceinline__ _Float16 h_from_bits(u16 u) {
    union { u16 u; _Float16 h; } c; c.u = u; return c.h;
}
__device__ __forceinline__ float h2f(u16 u) {
    return (float)h_from_bits(u);
}

// ---------------------------------------------------------------------------
// Sort-by-DST machinery: histogram -> 2-level exclusive scan.
// (scatter is fused into k_edge_mlp)
// ---------------------------------------------------------------------------
__global__ __launch_bounds__(256) void k_hist(const int* __restrict__ ei, u32* __restrict__ cnt) {
    int e = blockIdx.x * 256 + threadIdx.x;
    atomicAdd(&cnt[ei[NE + e]], 1u);
}

__global__ __launch_bounds__(256) void k_scan_a(const u32* __restrict__ cnt, u32* __restrict__ part) {
    __shared__ u32 sb[256];
    int t = threadIdx.x, i = blockIdx.x * 256 + t;
    u32 v = (i < NN) ? cnt[i] : 0u;
    sb[t] = v; __syncthreads();
    for (int off = 128; off > 0; off >>= 1) { if (t < off) sb[t] += sb[t + off]; __syncthreads(); }
    if (t == 0) part[blockIdx.x] = sb[0];
}

__global__ __launch_bounds__(256) void k_scan_b(u32* __restrict__ part, int nparts) {
    __shared__ u32 sb[256];
    int t = threadIdx.x;
    u32 v = (t < nparts) ? part[t] : 0u;
    sb[t] = v; __syncthreads();
    for (int off = 1; off < 256; off <<= 1) {
        u32 x = (t >= off) ? sb[t - off] : 0u; __syncthreads();
        sb[t] += x; __syncthreads();
    }
    if (t < nparts) part[t] = sb[t] - v;          // exclusive
}

__global__ __launch_bounds__(256) void k_scan_c(const u32* __restrict__ cnt, const u32* __restrict__ part,
                                                u32* __restrict__ row, u32* __restrict__ rowcur) {
    __shared__ u32 sb[256];
    int t = threadIdx.x, i = blockIdx.x * 256 + t;
    u32 v = (i < NN) ? cnt[i] : 0u;
    sb[t] = v; __syncthreads();
    for (int off = 1; off < 256; off <<= 1) {
        u32 x = (t >= off) ? sb[t - off] : 0u; __syncthreads();
        sb[t] += x; __syncthreads();
    }
    if (i < NN) {
        u32 ex = part[blockIdx.x] + sb[t] - v;
        row[i] = ex; rowcur[i] = ex;
    }
    if (i == 0) row[NN] = NE;
}

// ---------------------------------------------------------------------------
// Merged prep: feat f32->f16 copy (o < 400000, 8 elems each) + weight
// transposes (o-400000 in [0, 39936)).
// ---------------------------------------------------------------------------
__global__ __launch_bounds__(256) void k_prep(const float* __restrict__ feat,
                                              const float* __restrict__ Wtp,
                                              const float* __restrict__ W1,
                                              const float* __restrict__ W2,
                                              u16* __restrict__ feat16,
                                              u16* __restrict__ WtT,
                                              u16* __restrict__ W1T,
                                              u16* __restrict__ W2T) {
    int o = blockIdx.x * 256 + threadIdx.x;
    if (o < 400000) {
        const float* fp = feat + (size_t)o * 8;
        float4 v0 = *(const float4*)fp;
        float4 v1 = *(const float4*)(fp + 4);
        ushort4 o0{f2h_bits(v0.x), f2h_bits(v0.y), f2h_bits(v0.z), f2h_bits(v0.w)};
        ushort4 o1{f2h_bits(v1.x), f2h_bits(v1.y), f2h_bits(v1.z), f2h_bits(v1.w)};
        u16* op = feat16 + (size_t)o * 8;
        *(ushort4*)op = o0;
        *(ushort4*)(op + 4) = o1;
    } else {
        int q = o - 400000;
        if (q < 36864) {
            int g = q / 576, k = q % 576;
            int m = k >> 6, f = k & 63;
            WtT[q] = f2h_bits(Wtp[f * 576 + m * 64 + g]);
        } else if (q < 38912) {
            int i = q - 36864;
            int n = i >> 5, k = i & 31;
            W1T[i] = f2h_bits(W1[k * 64 + n]);
        } else if (q < 39936) {
            int i = q - 38912;
            int n = i >> 6, k = i & 63;
            W2T[i] = (n < 9) ? f2h_bits(W2[k * 9 + n]) : (u16)0;
        }
    }
}

// ---------------------------------------------------------------------------
// K1: per-edge weight MLP via MFMA (r14-proven) + FUSED scatter:
// each thread claims its dst-sorted position via rowcur atomicAdd, writes
// ssd[pos] up front, and stores s at pos in the tail (replaces k_scatter
// and the rank array round-trip).
// ---------------------------------------------------------------------------
__global__ __launch_bounds__(256, 2) void k_edge_mlp(
    const float* __restrict__ edge_attr, const float* __restrict__ edge_sh,
    const int* __restrict__ ei,
    const u16* __restrict__ W1T, const u16* __restrict__ W2T,
    const float* __restrict__ b1, const float* __restrict__ b2,
    u32* __restrict__ rowcur, u32* __restrict__ ssd,
    u16* __restrict__ s_sorted)            // [NE][12] f16 at pos
{
    __shared__ u16 sW1[64 * 36];           //  4,608 B
    __shared__ u16 sW2[16 * 68];           //  2,176 B
    __shared__ u16 sHid[4][64 * 68];       // 34,816 B (per-wave)
    __shared__ u16 sWout[256 * 12];        //  6,144 B
    const int t  = threadIdx.x;
    const int w  = t >> 6;
    const int l  = t & 63;
    const int e0 = blockIdx.x * 256;
    const int wbase = w << 6;

    // ---- fused scatter: claim sorted position, write ssd ----
    const int eIdx = e0 + t;
    const u32 s_ = (u32)ei[eIdx];
    const u32 d_ = (u32)ei[NE + eIdx];
    const u32 pos = atomicAdd(&rowcur[d_], 1u);
    ssd[pos] = s_ | (d_ << 16);

    // ---- stage W1T (1024 u32) + W2T (512 u32) into LDS ----
    {
        const u32* g1 = (const u32*)W1T;
        u32* l1 = (u32*)sW1;
        #pragma unroll
        for (int i = 0; i < 4; ++i) {
            int idx = i * 256 + t;                 // 0..1023
            int r = idx >> 4, c = idx & 15;
            l1[r * 18 + c] = g1[idx];
        }
        const u32* g2 = (const u32*)W2T;
        u32* l2 = (u32*)sW2;
        #pragma unroll
        for (int i = 0; i < 2; ++i) {
            int idx = i * 256 + t;                 // 0..511
            int r = idx >> 5, c = idx & 31;
            l2[r * 34 + c] = g2[idx];
        }
    }

    // ---- A-frags: attr rows -> f16 (8 contig k per lane) ----
    half8 aA[4];
    #pragma unroll
    for (int et = 0; et < 4; ++et) {
        const int e = e0 + wbase + (et << 4) + (l & 15);
        const float* ap = edge_attr + (size_t)e * 32 + ((l >> 4) << 3);
        float4 v0 = *(const float4*)ap;
        float4 v1 = *(const float4*)(ap + 4);
        aA[et] = half8{(_Float16)v0.x, (_Float16)v0.y, (_Float16)v0.z, (_Float16)v0.w,
                       (_Float16)v1.x, (_Float16)v1.y, (_Float16)v1.z, (_Float16)v1.w};
    }
    __syncthreads();

    // ---- GEMM1: [256x32] @ [32x64], K=32 ----
    f32x4 acc1[4][4] = {};
    {
        half8 bB[4];
        #pragma unroll
        for (int nt = 0; nt < 4; ++nt)
            bB[nt] = *(const half8*)&sW1[((nt << 4) + (l & 15)) * 36 + ((l >> 4) << 3)];
        #pragma unroll
        for (int et = 0; et < 4; ++et)
            #pragma unroll
            for (int nt = 0; nt < 4; ++nt)
                acc1[et][nt] = __builtin_amdgcn_mfma_f32_16x16x32_f16(aA[et], bB[nt], acc1[et][nt], 0, 0, 0);
    }

    // ---- +b1, silu -> per-wave LDS hid tile [64][68] f16 ----
    {
        float b1v[4];
        #pragma unroll
        for (int nt = 0; nt < 4; ++nt) b1v[nt] = b1[(nt << 4) + (l & 15)];
        #pragma unroll
        for (int et = 0; et < 4; ++et)
            #pragma unroll
            for (int nt = 0; nt < 4; ++nt)
                #pragma unroll
                for (int rg = 0; rg < 4; ++rg) {
                    int r = (et << 4) + ((l >> 4) << 2) + rg;
                    int c = (nt << 4) + (l & 15);
                    sHid[w][r * 68 + c] = f2h_bits(silu_f(acc1[et][nt][rg] + b1v[nt]));
                }
    }
    __syncthreads();

    // ---- GEMM2: [256x64] @ [64x16], K=64 ----
    f32x4 acc2[4] = {};
    #pragma unroll
    for (int tt = 0; tt < 2; ++tt) {
        half8 b2f = *(const half8*)&sW2[(l & 15) * 68 + tt * 32 + ((l >> 4) << 3)];
        #pragma unroll
        for (int et = 0; et < 4; ++et) {
            half8 a2 = *(const half8*)&sHid[w][((et << 4) + (l & 15)) * 68 + tt * 32 + ((l >> 4) << 3)];
            acc2[et] = __builtin_amdgcn_mfma_f32_16x16x32_f16(a2, b2f, acc2[et], 0, 0, 0);
        }
    }

    // ---- +b2 -> LDS w tile [256][12] ----
    {
        const int m = l & 15;
        if (m < 9) {
            const float b2v = b2[m];
            #pragma unroll
            for (int et = 0; et < 4; ++et)
                #pragma unroll
                for (int rg = 0; rg < 4; ++rg) {
                    int r = wbase + (et << 4) + ((l >> 4) << 2) + rg;
                    sWout[r * 12 + m] = f2h_bits(acc2[et][rg] + b2v);
                }
        }
    }
    __syncthreads();

    // ---- proven tail: s = sh * w; store at fused-scatter pos ----
    const size_t e = (size_t)eIdx;
    const float* sh = edge_sh + e * 9;
    u16 sw[12];
    #pragma unroll
    for (int m = 0; m < 9; ++m) sw[m] = f2h_bits(sh[m] * h2f(sWout[t * 12 + m]));
    sw[9] = sw[10] = sw[11] = 0;

    u16* dp = s_sorted + (size_t)pos * 12;
    ushort4 v0{sw[0], sw[1], sw[2],  sw[3]};
    ushort4 v1{sw[4], sw[5], sw[6],  sw[7]};
    ushort4 v2{sw[8], sw[9], sw[10], sw[11]};
    *(ushort4*)(dp + 0) = v0;
    *(ushort4*)(dp + 4) = v1;
    *(ushort4*)(dp + 8) = v2;
}

// ---------------------------------------------------------------------------
// K3: MFMA combine — 512 threads (8 waves x 2 e-tiles), r17-proven structure.
// s loads vectorized: 3 x ushort4 per e-tile (VMEM/thread 24 -> 12).
// ---------------------------------------------------------------------------
union SmU {
    u16 wt[64 * 584];      // 74,752 B  (staged WtT, padded rows)
    u16 msg[256 * 68];     // 34,816 B  (C spill, f16)
};

__global__ __launch_bounds__(512, 4) void k_combine_mfma(
    const u32* __restrict__ ssd,  const u32* __restrict__ row,
    const u16* __restrict__ s_sorted,
    const u16* __restrict__ feat16, const u16* __restrict__ WtT,
    float* __restrict__ out)
{
    __shared__ SmU sm;
    const int t  = threadIdx.x;
    const int w  = t >> 6;                 // 0..7
    const int l  = t & 63;
    const int p0 = blockIdx.x * 256;
    const int rbase = w << 5;              // 32 edges per wave

    // ---- hoisted global loads: srcs, 4 feat gathers, s (vectorized) ----
    u32 srcr[2];
    #pragma unroll
    for (int et = 0; et < 2; ++et)
        srcr[et] = ssd[p0 + rbase + (et << 4) + (l & 15)] & 0xFFFFu;

    half8 h16[2][2];                        // [et][fhalf]
    #pragma unroll
    for (int et = 0; et < 2; ++et)
        #pragma unroll
        for (int fh = 0; fh < 2; ++fh)
            h16[et][fh] = *(const half8*)(feat16 +
                (size_t)srcr[et] * 64 + (fh << 5) + ((l >> 4) << 3));

    half2v s2[2][9];                        // {s,s} pairs
    #pragma unroll
    for (int et = 0; et < 2; ++et) {
        const u16* sp = s_sorted + (size_t)(p0 + rbase + (et << 4) + (l & 15)) * 12;
        ushort4 sa = *(const ushort4*)(sp + 0);
        ushort4 sb = *(const ushort4*)(sp + 4);
        ushort4 sc = *(const ushort4*)(sp + 8);
        u16 sv[9] = {sa.x, sa.y, sa.z, sa.w, sb.x, sb.y, sb.z, sb.w, sc.x};
        #pragma unroll
        for (int m = 0; m < 9; ++m) {
            _Float16 h = h_from_bits(sv[m]);
            s2[et][m] = half2v{h, h};
        }
    }

    // ---- stage WtT [64][576] -> LDS [64][584] in 16B chunks ----
    {
        const uint4* gsrc = (const uint4*)WtT;         // [64*72] 16B chunks
        uint4* lw = (uint4*)sm.wt;                     // 584/8 = 73 chunks/row
        #pragma unroll
        for (int i = 0; i < 9; ++i) {
            int c = i * 512 + t;                       // 0..4607
            int r = c / 72, q = c - r * 72;
            lw[r * 73 + q] = gsrc[c];
        }
    }
    __syncthreads();

    f32x4 acc[2][4] = {};
    #pragma unroll
    for (int fhalf = 0; fhalf < 2; ++fhalf) {
        #pragma unroll
        for (int m = 0; m < 9; ++m) {
            const int tt = (m << 1) + fhalf;          // K-slice: k = tt*32 ..
            half8 bfr[4];
            #pragma unroll
            for (int gt = 0; gt < 4; ++gt)
                bfr[gt] = *(const half8*)&sm.wt[
                    (((gt << 4) + (l & 15)) * 584) + tt * 32 + ((l >> 4) << 3)];
            #pragma unroll
            for (int et = 0; et < 2; ++et) {
                union { half2v h2[4]; half8 v; } A;
                const union { half8 v; half2v h2[4]; } H = { h16[et][fhalf] };
                A.h2[0] = H.h2[0] * s2[et][m];         // v_pk_mul_f16
                A.h2[1] = H.h2[1] * s2[et][m];
                A.h2[2] = H.h2[2] * s2[et][m];
                A.h2[3] = H.h2[3] * s2[et][m];
                #pragma unroll
                for (int gt = 0; gt < 4; ++gt)
                    acc[et][gt] = __builtin_amdgcn_mfma_f32_16x16x32_f16(A.v, bfr[gt], acc[et][gt], 0, 0, 0);
            }
        }
    }
    __syncthreads();   // all B-reads done before msg overwrites the union

    // ---- C tiles -> LDS msg[256][68] f16 (disjoint cells) ----
    #pragma unroll
    for (int et = 0; et < 2; ++et)
        #pragma unroll
        for (int gt = 0; gt < 4; ++gt)
            #pragma unroll
            for (int rg = 0; rg < 4; ++rg) {
                int rloc = rbase + (et << 4) + ((l >> 4) << 2) + rg;   // C row = edge
                int col  = (gt << 4) + (l & 15);                       // C col = g
                sm.msg[rloc * 68 + col] = f2h_bits(acc[et][gt][rg]);
            }
    __syncthreads();

    // ---- segmented per-node reduction; one atomic per (node,g) per block ----
    const int dfirst = (int)(ssd[p0] >> 16);
    const int dlast  = (int)(ssd[p0 + 255] >> 16);
    for (int n = dfirst + w; n <= dlast; n += 8) {
        int a = (int)row[n]     - p0; if (a < 0)   a = 0;
        int b = (int)row[n + 1] - p0; if (b > 256) b = 256;
        if (a < b) {
            float v = 0.f;
            for (int p = a; p < b; ++p) v += h2f(sm.msg[p * 68 + l]);
            atomicAdd(out + (size_t)n * 64 + l, v * 0.25f);    // 1/sqrt(16)
        }
    }
}

// ---------------------------------------------------------------------------
// K4: FiLM, in-place on d_out.
// ---------------------------------------------------------------------------
__global__ __launch_bounds__(256) void k_film(
    const float* __restrict__ c_noise,
    const float* __restrict__ Wn1, const float* __restrict__ bn1,
    const float* __restrict__ Wn2, const float* __restrict__ bn2,
    float* __restrict__ out)
{
    const int n    = (blockIdx.x * 256 + threadIdx.x) >> 6;
    const int lane = threadIdx.x & 63;
    const float c  = c_noise[n];
    const float hid = silu_f(fmaf(c, Wn1[lane], bn1[lane]));
    float g = bn2[lane], b = bn2[64 + lane];
    for (int h = 0; h < 64; ++h) {
        const float hv = __shfl(hid, h, 64);
        g = fmaf(hv, Wn2[h * 128 + lane],      g);
        b = fmaf(hv, Wn2[h * 128 + 64 + lane], b);
    }
    const size_t i = (size_t)n * 64 + lane;
    out[i] = fmaf(out[i], 1.f + g, b);
}

// ---------------------------------------------------------------------------
extern "C" void kernel_launch(void* const* d_in, const int* in_sizes, int n_in,
                              void* d_out, int out_size, void* d_ws, size_t ws_size,
                              hipStream_t stream) {
    const float* features   = (const float*)d_in[0];
    const int*   edge_index = (const int*)  d_in[1];
    const float* edge_attr  = (const float*)d_in[2];
    const float* edge_sh    = (const float*)d_in[3];
    const float* c_noise    = (const float*)d_in[4];
    const float* W1  = (const float*)d_in[5];
    const float* b1  = (const float*)d_in[6];
    const float* W2  = (const float*)d_in[7];
    const float* b2  = (const float*)d_in[8];
    const float* Wtp = (const float*)d_in[9];
    const float* Wn1 = (const float*)d_in[10];
    const float* bn1 = (const float*)d_in[11];
    const float* Wn2 = (const float*)d_in[12];
    const float* bn2 = (const float*)d_in[13];
    float* out = (float*)d_out;

    char* ws = (char*)d_ws;
    u16* feat16   = (u16*)(ws);                    //  6,400,000 B
    u16* s_sorted = (u16*)(ws +  6400000);         // 19,200,000 B
    u32* ssd      = (u32*)(ws + 25600000);         //  3,200,000 B
    u32* row      = (u32*)(ws + 28800000);         //    200,016 B (NN+1)
    u32* rowcur   = (u32*)(ws + 29000016);         //    200,000 B
    u32* cnt      = (u32*)(ws + 29200016);         //    200,000 B
    u32* part     = (u32*)(ws + 29400016);         //      1,024 B
    u16* WtT      = (u16*)(ws + 29401040);         //     73,728 B
    u16* W1T      = (u16*)(ws + 29474768);         //      4,096 B
    u16* W2T      = (u16*)(ws + 29478864);         //      2,048 B  (end ~29.5 MB)

    const int nparts = (NN + 255) / 256;           // 196

    hipMemsetAsync(cnt, 0, (size_t)NN * 4, stream);
    hipMemsetAsync(out, 0, (size_t)NN * 64 * sizeof(float), stream);

    k_hist   <<<NE / 256, 256, 0, stream>>>(edge_index, cnt);
    k_scan_a <<<nparts, 256, 0, stream>>>(cnt, part);
    k_scan_b <<<1, 256, 0, stream>>>(part, nparts);
    k_scan_c <<<nparts, 256, 0, stream>>>(cnt, part, row, rowcur);

    k_prep   <<<(400000 + 39936 + 255) / 256, 256, 0, stream>>>(
        features, Wtp, W1, W2, feat16, WtT, W1T, W2T);

    k_edge_mlp<<<NE / 256, 256, 0, stream>>>(edge_attr, edge_sh, edge_index,
                                             W1T, W2T, b1, b2,
                                             rowcur, ssd, s_sorted);

    k_combine_mfma<<<NE / 256, 512, 0, stream>>>(ssd, row, s_sorted,
                                                 feat16, WtT, out);

    k_film<<<(NN * 64) / 256, 256, 0, stream>>>(c_noise, Wn1, bn1, Wn2, bn2, out);
}

// Round 19
// 252.905 us; speedup vs baseline: 1.2170x; 1.0238x over previous
//
#include <hip/hip_runtime.h>
#include <hip/hip_bf16.h>

#define NN 50000
#define NE 800000

typedef unsigned int u32;
typedef unsigned short u16;
typedef __attribute__((ext_vector_type(2))) _Float16 half2v;
typedef __attribute__((ext_vector_type(8))) _Float16 half8;
typedef __attribute__((ext_vector_type(4))) float f32x4;    // MFMA C/D

__device__ __forceinline__ float silu_f(float x) {
    return x * (1.0f / (1.0f + __expf(-x)));
}
__device__ __forceinline__ u16 f2h_bits(float f) {          // f32 -> f16 (HW RNE)
    union { _Float16 h; u16 u; } c; c.h = (_Float16)f; return c.u;
}
__device__ __forceinline__ _Float16 h_from_bits(u16 u) {
    union { u16 u; _Float16 h; } c; c.u = u; return c.h;
}
__device__ __forceinline__ float h2f(u16 u) {
    return (float)h_from_bits(u);
}

// ---------------------------------------------------------------------------
// Scan machinery (hist fused into k_prep_hist; scatter fused into k_edge_mlp)
// ---------------------------------------------------------------------------
__global__ __launch_bounds__(256) void k_scan_a(const u32* __restrict__ cnt, u32* __restrict__ part) {
    __shared__ u32 sb[256];
    int t = threadIdx.x, i = blockIdx.x * 256 + t;
    u32 v = (i < NN) ? cnt[i] : 0u;
    sb[t] = v; __syncthreads();
    for (int off = 128; off > 0; off >>= 1) { if (t < off) sb[t] += sb[t + off]; __syncthreads(); }
    if (t == 0) part[blockIdx.x] = sb[0];
}

__global__ __launch_bounds__(256) void k_scan_b(u32* __restrict__ part, int nparts) {
    __shared__ u32 sb[256];
    int t = threadIdx.x;
    u32 v = (t < nparts) ? part[t] : 0u;
    sb[t] = v; __syncthreads();
    for (int off = 1; off < 256; off <<= 1) {
        u32 x = (t >= off) ? sb[t - off] : 0u; __syncthreads();
        sb[t] += x; __syncthreads();
    }
    if (t < nparts) part[t] = sb[t] - v;          // exclusive
}

__global__ __launch_bounds__(256) void k_scan_c(const u32* __restrict__ cnt, const u32* __restrict__ part,
                                                u32* __restrict__ row, u32* __restrict__ rowcur) {
    __shared__ u32 sb[256];
    int t = threadIdx.x, i = blockIdx.x * 256 + t;
    u32 v = (i < NN) ? cnt[i] : 0u;
    sb[t] = v; __syncthreads();
    for (int off = 1; off < 256; off <<= 1) {
        u32 x = (t >= off) ? sb[t - off] : 0u; __syncthreads();
        sb[t] += x; __syncthreads();
    }
    if (i < NN) {
        u32 ex = part[blockIdx.x] + sb[t] - v;
        row[i] = ex; rowcur[i] = ex;
    }
    if (i == 0) row[NN] = NE;
}

// ---------------------------------------------------------------------------
// Merged prep + hist: o<800000 -> dst histogram; [800000,1200000) -> feat16
// (8 elems each); [1200000,1239936) -> weight transposes.
// ---------------------------------------------------------------------------
__global__ __launch_bounds__(256) void k_prep_hist(const int* __restrict__ ei,
                                                   const float* __restrict__ feat,
                                                   const float* __restrict__ Wtp,
                                                   const float* __restrict__ W1,
                                                   const float* __restrict__ W2,
                                                   u32* __restrict__ cnt,
                                                   u16* __restrict__ feat16,
                                                   u16* __restrict__ WtT,
                                                   u16* __restrict__ W1T,
                                                   u16* __restrict__ W2T) {
    int o = blockIdx.x * 256 + threadIdx.x;
    if (o < 800000) {
        atomicAdd(&cnt[ei[NE + o]], 1u);
    } else if (o < 1200000) {
        int i = o - 800000;
        const float* fp = feat + (size_t)i * 8;
        float4 v0 = *(const float4*)fp;
        float4 v1 = *(const float4*)(fp + 4);
        ushort4 o0{f2h_bits(v0.x), f2h_bits(v0.y), f2h_bits(v0.z), f2h_bits(v0.w)};
        ushort4 o1{f2h_bits(v1.x), f2h_bits(v1.y), f2h_bits(v1.z), f2h_bits(v1.w)};
        u16* op = feat16 + (size_t)i * 8;
        *(ushort4*)op = o0;
        *(ushort4*)(op + 4) = o1;
    } else {
        int q = o - 1200000;
        if (q < 36864) {
            int g = q / 576, k = q % 576;
            int m = k >> 6, f = k & 63;
            WtT[q] = f2h_bits(Wtp[f * 576 + m * 64 + g]);
        } else if (q < 38912) {
            int i = q - 36864;
            int n = i >> 5, k = i & 31;
            W1T[i] = f2h_bits(W1[k * 64 + n]);
        } else if (q < 39936) {
            int i = q - 38912;
            int n = i >> 6, k = i & 63;
            W2T[i] = (n < 9) ? f2h_bits(W2[k * 9 + n]) : (u16)0;
        }
    }
}

// ---------------------------------------------------------------------------
// K1: per-edge weight MLP via MFMA (r14-proven) + fused scatter (r18-proven).
// ---------------------------------------------------------------------------
__global__ __launch_bounds__(256, 2) void k_edge_mlp(
    const float* __restrict__ edge_attr, const float* __restrict__ edge_sh,
    const int* __restrict__ ei,
    const u16* __restrict__ W1T, const u16* __restrict__ W2T,
    const float* __restrict__ b1, const float* __restrict__ b2,
    u32* __restrict__ rowcur, u32* __restrict__ ssd,
    u16* __restrict__ s_sorted)            // [NE][12] f16 at pos
{
    __shared__ u16 sW1[64 * 36];           //  4,608 B
    __shared__ u16 sW2[16 * 68];           //  2,176 B
    __shared__ u16 sHid[4][64 * 68];       // 34,816 B (per-wave)
    __shared__ u16 sWout[256 * 12];        //  6,144 B
    const int t  = threadIdx.x;
    const int w  = t >> 6;
    const int l  = t & 63;
    const int e0 = blockIdx.x * 256;
    const int wbase = w << 6;

    // ---- fused scatter: claim sorted position, write ssd ----
    const int eIdx = e0 + t;
    const u32 s_ = (u32)ei[eIdx];
    const u32 d_ = (u32)ei[NE + eIdx];
    const u32 pos = atomicAdd(&rowcur[d_], 1u);
    ssd[pos] = s_ | (d_ << 16);

    // ---- stage W1T (1024 u32) + W2T (512 u32) into LDS ----
    {
        const u32* g1 = (const u32*)W1T;
        u32* l1 = (u32*)sW1;
        #pragma unroll
        for (int i = 0; i < 4; ++i) {
            int idx = i * 256 + t;                 // 0..1023
            int r = idx >> 4, c = idx & 15;
            l1[r * 18 + c] = g1[idx];
        }
        const u32* g2 = (const u32*)W2T;
        u32* l2 = (u32*)sW2;
        #pragma unroll
        for (int i = 0; i < 2; ++i) {
            int idx = i * 256 + t;                 // 0..511
            int r = idx >> 5, c = idx & 31;
            l2[r * 34 + c] = g2[idx];
        }
    }

    // ---- A-frags: attr rows -> f16 (8 contig k per lane) ----
    half8 aA[4];
    #pragma unroll
    for (int et = 0; et < 4; ++et) {
        const int e = e0 + wbase + (et << 4) + (l & 15);
        const float* ap = edge_attr + (size_t)e * 32 + ((l >> 4) << 3);
        float4 v0 = *(const float4*)ap;
        float4 v1 = *(const float4*)(ap + 4);
        aA[et] = half8{(_Float16)v0.x, (_Float16)v0.y, (_Float16)v0.z, (_Float16)v0.w,
                       (_Float16)v1.x, (_Float16)v1.y, (_Float16)v1.z, (_Float16)v1.w};
    }
    __syncthreads();

    // ---- GEMM1: [256x32] @ [32x64], K=32 ----
    f32x4 acc1[4][4] = {};
    {
        half8 bB[4];
        #pragma unroll
        for (int nt = 0; nt < 4; ++nt)
            bB[nt] = *(const half8*)&sW1[((nt << 4) + (l & 15)) * 36 + ((l >> 4) << 3)];
        #pragma unroll
        for (int et = 0; et < 4; ++et)
            #pragma unroll
            for (int nt = 0; nt < 4; ++nt)
                acc1[et][nt] = __builtin_amdgcn_mfma_f32_16x16x32_f16(aA[et], bB[nt], acc1[et][nt], 0, 0, 0);
    }

    // ---- +b1, silu -> per-wave LDS hid tile [64][68] f16 ----
    {
        float b1v[4];
        #pragma unroll
        for (int nt = 0; nt < 4; ++nt) b1v[nt] = b1[(nt << 4) + (l & 15)];
        #pragma unroll
        for (int et = 0; et < 4; ++et)
            #pragma unroll
            for (int nt = 0; nt < 4; ++nt)
                #pragma unroll
                for (int rg = 0; rg < 4; ++rg) {
                    int r = (et << 4) + ((l >> 4) << 2) + rg;
                    int c = (nt << 4) + (l & 15);
                    sHid[w][r * 68 + c] = f2h_bits(silu_f(acc1[et][nt][rg] + b1v[nt]));
                }
    }
    __syncthreads();

    // ---- GEMM2: [256x64] @ [64x16], K=64 ----
    f32x4 acc2[4] = {};
    #pragma unroll
    for (int tt = 0; tt < 2; ++tt) {
        half8 b2f = *(const half8*)&sW2[(l & 15) * 68 + tt * 32 + ((l >> 4) << 3)];
        #pragma unroll
        for (int et = 0; et < 4; ++et) {
            half8 a2 = *(const half8*)&sHid[w][((et << 4) + (l & 15)) * 68 + tt * 32 + ((l >> 4) << 3)];
            acc2[et] = __builtin_amdgcn_mfma_f32_16x16x32_f16(a2, b2f, acc2[et], 0, 0, 0);
        }
    }

    // ---- +b2 -> LDS w tile [256][12] ----
    {
        const int m = l & 15;
        if (m < 9) {
            const float b2v = b2[m];
            #pragma unroll
            for (int et = 0; et < 4; ++et)
                #pragma unroll
                for (int rg = 0; rg < 4; ++rg) {
                    int r = wbase + (et << 4) + ((l >> 4) << 2) + rg;
                    sWout[r * 12 + m] = f2h_bits(acc2[et][rg] + b2v);
                }
        }
    }
    __syncthreads();

    // ---- proven tail: s = sh * w; store at fused-scatter pos ----
    const size_t e = (size_t)eIdx;
    const float* sh = edge_sh + e * 9;
    u16 sw[12];
    #pragma unroll
    for (int m = 0; m < 9; ++m) sw[m] = f2h_bits(sh[m] * h2f(sWout[t * 12 + m]));
    sw[9] = sw[10] = sw[11] = 0;

    u16* dp = s_sorted + (size_t)pos * 12;
    ushort4 v0{sw[0], sw[1], sw[2],  sw[3]};
    ushort4 v1{sw[4], sw[5], sw[6],  sw[7]};
    ushort4 v2{sw[8], sw[9], sw[10], sw[11]};
    *(ushort4*)(dp + 0) = v0;
    *(ushort4*)(dp + 4) = v1;
    *(ushort4*)(dp + 8) = v2;
}

// ---------------------------------------------------------------------------
// K3: MFMA combine — 512 threads (8 waves x 2 e-tiles).  B-fragment loads
// DOUBLE-BUFFERED (load slice j+1 while slice j's MFMAs issue): breaks the
// ds_read->lgkmcnt->MFMA serial chain that pinned r14-r18 at 89 µs (the
// (512,4) 128-reg cap left no VGPRs to prefetch; MfmaUtil 27% ≈ 40/160cyc).
// __launch_bounds__(512,2) gives the allocator headroom (~70+64 regs -> 3
// waves/SIMD; r17 proved occupancy in this range is not the lever).
// ---------------------------------------------------------------------------
union SmU {
    u16 wt[64 * 584];      // 74,752 B  (staged WtT, padded rows)
    u16 msg[256 * 68];     // 34,816 B  (C spill, f16)
};

__global__ __launch_bounds__(512, 2) void k_combine_mfma(
    const u32* __restrict__ ssd,  const u32* __restrict__ row,
    const u16* __restrict__ s_sorted,
    const u16* __restrict__ feat16, const u16* __restrict__ WtT,
    float* __restrict__ out)
{
    __shared__ SmU sm;
    const int t  = threadIdx.x;
    const int w  = t >> 6;                 // 0..7
    const int l  = t & 63;
    const int p0 = blockIdx.x * 256;
    const int rbase = w << 5;              // 32 edges per wave

    // ---- hoisted global loads: srcs, 4 feat gathers, s (vectorized) ----
    u32 srcr[2];
    #pragma unroll
    for (int et = 0; et < 2; ++et)
        srcr[et] = ssd[p0 + rbase + (et << 4) + (l & 15)] & 0xFFFFu;

    half8 h16[2][2];                        // [et][fhalf]
    #pragma unroll
    for (int et = 0; et < 2; ++et)
        #pragma unroll
        for (int fh = 0; fh < 2; ++fh)
            h16[et][fh] = *(const half8*)(feat16 +
                (size_t)srcr[et] * 64 + (fh << 5) + ((l >> 4) << 3));

    half2v s2[2][9];                        // {s,s} pairs
    #pragma unroll
    for (int et = 0; et < 2; ++et) {
        const u16* sp = s_sorted + (size_t)(p0 + rbase + (et << 4) + (l & 15)) * 12;
        ushort4 sa = *(const ushort4*)(sp + 0);
        ushort4 sb = *(const ushort4*)(sp + 4);
        ushort4 sc = *(const ushort4*)(sp + 8);
        u16 sv[9] = {sa.x, sa.y, sa.z, sa.w, sb.x, sb.y, sb.z, sb.w, sc.x};
        #pragma unroll
        for (int m = 0; m < 9; ++m) {
            _Float16 h = h_from_bits(sv[m]);
            s2[et][m] = half2v{h, h};
        }
    }

    // ---- stage WtT [64][576] -> LDS [64][584] in 16B chunks ----
    {
        const uint4* gsrc = (const uint4*)WtT;         // [64*72] 16B chunks
        uint4* lw = (uint4*)sm.wt;                     // 584/8 = 73 chunks/row
        #pragma unroll
        for (int i = 0; i < 9; ++i) {
            int c = i * 512 + t;                       // 0..4607
            int r = c / 72, q = c - r * 72;
            lw[r * 73 + q] = gsrc[c];
        }
    }
    __syncthreads();

    // ---- K loop: 18 slices, B-frags double-buffered ----
    // j<9: fhalf=0, m=j, tt=2j;  j>=9: fhalf=1, m=j-9, tt=2(j-9)+1
    half8 bA[4], bB_[4];
    #pragma unroll
    for (int gt = 0; gt < 4; ++gt)
        bA[gt] = *(const half8*)&sm.wt[(((gt << 4) + (l & 15)) * 584) + ((l >> 4) << 3)];  // tt=0

    f32x4 acc[2][4] = {};
    #pragma unroll
    for (int j = 0; j < 18; ++j) {
        const int fh = (j < 9) ? 0 : 1;
        const int m  = (j < 9) ? j : j - 9;
        half8* cur = (j & 1) ? bB_ : bA;        // static under full unroll
        half8* nxt = (j & 1) ? bA  : bB_;
        if (j < 17) {
            const int jn  = j + 1;
            const int ttn = (jn < 9) ? (jn << 1) : (((jn - 9) << 1) + 1);
            #pragma unroll
            for (int gt = 0; gt < 4; ++gt)
                nxt[gt] = *(const half8*)&sm.wt[
                    (((gt << 4) + (l & 15)) * 584) + ttn * 32 + ((l >> 4) << 3)];
        }
        #pragma unroll
        for (int et = 0; et < 2; ++et) {
            union { half2v h2[4]; half8 v; } A;
            const union { half8 v; half2v h2[4]; } H = { h16[et][fh] };
            A.h2[0] = H.h2[0] * s2[et][m];         // v_pk_mul_f16
            A.h2[1] = H.h2[1] * s2[et][m];
            A.h2[2] = H.h2[2] * s2[et][m];
            A.h2[3] = H.h2[3] * s2[et][m];
            #pragma unroll
            for (int gt = 0; gt < 4; ++gt)
                acc[et][gt] = __builtin_amdgcn_mfma_f32_16x16x32_f16(A.v, cur[gt], acc[et][gt], 0, 0, 0);
        }
    }
    __syncthreads();   // all B-reads done before msg overwrites the union

    // ---- C tiles -> LDS msg[256][68] f16 (disjoint cells) ----
    #pragma unroll
    for (int et = 0; et < 2; ++et)
        #pragma unroll
        for (int gt = 0; gt < 4; ++gt)
            #pragma unroll
            for (int rg = 0; rg < 4; ++rg) {
                int rloc = rbase + (et << 4) + ((l >> 4) << 2) + rg;   // C row = edge
                int col  = (gt << 4) + (l & 15);                       // C col = g
                sm.msg[rloc * 68 + col] = f2h_bits(acc[et][gt][rg]);
            }
    __syncthreads();

    // ---- segmented per-node reduction; one atomic per (node,g) per block ----
    const int dfirst = (int)(ssd[p0] >> 16);
    const int dlast  = (int)(ssd[p0 + 255] >> 16);
    for (int n = dfirst + w; n <= dlast; n += 8) {
        int a = (int)row[n]     - p0; if (a < 0)   a = 0;
        int b = (int)row[n + 1] - p0; if (b > 256) b = 256;
        if (a < b) {
            float v = 0.f;
            for (int p = a; p < b; ++p) v += h2f(sm.msg[p * 68 + l]);
            atomicAdd(out + (size_t)n * 64 + l, v * 0.25f);    // 1/sqrt(16)
        }
    }
}

// ---------------------------------------------------------------------------
// K4: FiLM, in-place on d_out.
// ---------------------------------------------------------------------------
__global__ __launch_bounds__(256) void k_film(
    const float* __restrict__ c_noise,
    const float* __restrict__ Wn1, const float* __restrict__ bn1,
    const float* __restrict__ Wn2, const float* __restrict__ bn2,
    float* __restrict__ out)
{
    const int n    = (blockIdx.x * 256 + threadIdx.x) >> 6;
    const int lane = threadIdx.x & 63;
    const float c  = c_noise[n];
    const float hid = silu_f(fmaf(c, Wn1[lane], bn1[lane]));
    float g = bn2[lane], b = bn2[64 + lane];
    for (int h = 0; h < 64; ++h) {
        const float hv = __shfl(hid, h, 64);
        g = fmaf(hv, Wn2[h * 128 + lane],      g);
        b = fmaf(hv, Wn2[h * 128 + 64 + lane], b);
    }
    const size_t i = (size_t)n * 64 + lane;
    out[i] = fmaf(out[i], 1.f + g, b);
}

// ---------------------------------------------------------------------------
extern "C" void kernel_launch(void* const* d_in, const int* in_sizes, int n_in,
                              void* d_out, int out_size, void* d_ws, size_t ws_size,
                              hipStream_t stream) {
    const float* features   = (const float*)d_in[0];
    const int*   edge_index = (const int*)  d_in[1];
    const float* edge_attr  = (const float*)d_in[2];
    const float* edge_sh    = (const float*)d_in[3];
    const float* c_noise    = (const float*)d_in[4];
    const float* W1  = (const float*)d_in[5];
    const float* b1  = (const float*)d_in[6];
    const float* W2  = (const float*)d_in[7];
    const float* b2  = (const float*)d_in[8];
    const float* Wtp = (const float*)d_in[9];
    const float* Wn1 = (const float*)d_in[10];
    const float* bn1 = (const float*)d_in[11];
    const float* Wn2 = (const float*)d_in[12];
    const float* bn2 = (const float*)d_in[13];
    float* out = (float*)d_out;

    char* ws = (char*)d_ws;
    u16* feat16   = (u16*)(ws);                    //  6,400,000 B
    u16* s_sorted = (u16*)(ws +  6400000);         // 19,200,000 B
    u32* ssd      = (u32*)(ws + 25600000);         //  3,200,000 B
    u32* row      = (u32*)(ws + 28800000);         //    200,016 B (NN+1)
    u32* rowcur   = (u32*)(ws + 29000016);         //    200,000 B
    u32* cnt      = (u32*)(ws + 29200016);         //    200,000 B
    u32* part     = (u32*)(ws + 29400016);         //      1,024 B
    u16* WtT      = (u16*)(ws + 29401040);         //     73,728 B
    u16* W1T      = (u16*)(ws + 29474768);         //      4,096 B
    u16* W2T      = (u16*)(ws + 29478864);         //      2,048 B  (end ~29.5 MB)

    const int nparts = (NN + 255) / 256;           // 196

    hipMemsetAsync(cnt, 0, (size_t)NN * 4, stream);
    hipMemsetAsync(out, 0, (size_t)NN * 64 * sizeof(float), stream);

    k_prep_hist<<<(1239936 + 255) / 256, 256, 0, stream>>>(
        edge_index, features, Wtp, W1, W2, cnt, feat16, WtT, W1T, W2T);

    k_scan_a <<<nparts, 256, 0, stream>>>(cnt, part);
    k_scan_b <<<1, 256, 0, stream>>>(part, nparts);
    k_scan_c <<<nparts, 256, 0, stream>>>(cnt, part, row, rowcur);

    k_edge_mlp<<<NE / 256, 256, 0, stream>>>(edge_attr, edge_sh, edge_index,
                                             W1T, W2T, b1, b2,
                                             rowcur, ssd, s_sorted);

    k_combine_mfma<<<NE / 256, 512, 0, stream>>>(ssd, row, s_sorted,
                                                 feat16, WtT, out);

    k_film<<<(NN * 64) / 256, 256, 0, stream>>>(c_noise, Wn1, bn1, Wn2, bn2, out);
}